// Round 5
// baseline (684.825 us; speedup 1.0000x reference)
//
#include <hip/hip_runtime.h>

// TransformerBlock fused pipeline for MI355X (gfx950).
// SEQ=2048, D_MODEL=2048, H=16, DK=DV=128, DFF=8192. fp32 in/out.
//
// R5: R2-exact passing pipeline (m97 k_gemm_bt + split-K, split3, flash,
// add_ln) + two DEAD-OUTPUT probes of the 8-phase 256^2 gemm8:
//   probe A: static 128KB LDS (R3/R4 config)  -> does it even launch?
//   probe B: dynamic 128KB LDS + hipFuncSetAttribute -> does the fix path?
// Probe outputs land in vtp and are fully overwritten by the real vt GEMM.
// R3/R4 failed with IDENTICAL absmax across different schedules => shared
// launch config (512thr/128KB static LDS) suspected of silent launch failure.

typedef __bf16 bf16;
typedef __attribute__((ext_vector_type(8))) __bf16 bf16x8;
typedef __attribute__((ext_vector_type(4))) __bf16 bf16x4;
typedef __attribute__((ext_vector_type(4))) float f32x4;

#define MFMA(a, b, c) __builtin_amdgcn_mfma_f32_16x16x32_bf16((a), (b), (c), 0, 0, 0)
#define NEG_INF (-3.402823466e38f)

__device__ __forceinline__ void cp16(void* lds, const void* g) {
  __builtin_amdgcn_global_load_lds(
      (const __attribute__((address_space(1))) unsigned int*)g,
      (__attribute__((address_space(3))) unsigned int*)lds, 16, 0, 0);
}

#define SBAR() __builtin_amdgcn_sched_barrier(0)
#define GBAR()                              \
  do {                                      \
    asm volatile("" ::: "memory");          \
    __builtin_amdgcn_s_barrier();           \
    asm volatile("" ::: "memory");          \
  } while (0)
#define LGKM0()                                         \
  do {                                                  \
    asm volatile("s_waitcnt lgkmcnt(0)" ::: "memory");  \
    __builtin_amdgcn_sched_barrier(0);                  \
  } while (0)
#define VMC6()                                          \
  do {                                                  \
    asm volatile("s_waitcnt vmcnt(6)" ::: "memory");    \
    __builtin_amdgcn_sched_barrier(0);                  \
  } while (0)

// ---------------- converts ----------------

__global__ void k_split_x(const float* __restrict__ x, bf16* __restrict__ xh,
                          bf16* __restrict__ xl) {
  int i = blockIdx.x * 256 + threadIdx.x;
  f32x4 v = ((const f32x4*)x)[i];
  bf16x4 h, l;
#pragma unroll
  for (int j = 0; j < 4; ++j) {
    bf16 hi = (bf16)v[j];
    h[j] = hi;
    l[j] = (bf16)(v[j] - (float)hi);
  }
  ((bf16x4*)xh)[i] = h;
  ((bf16x4*)xl)[i] = l;
}

template <bool SPLIT>
__global__ void k_tcvt(const float* __restrict__ in, bf16* __restrict__ oh,
                       bf16* __restrict__ ol, int R, int C) {
  __shared__ float t[64][65];
  long zoff = (long)blockIdx.z * R * C;
  int c0 = blockIdx.x * 64, r0 = blockIdx.y * 64;
  int cc = threadIdx.x & 63, rr = threadIdx.x >> 6;
#pragma unroll
  for (int i = 0; i < 16; ++i) {
    int r = i * 4 + rr;
    t[r][cc] = in[zoff + (long)(r0 + r) * C + c0 + cc];
  }
  __syncthreads();
#pragma unroll
  for (int i = 0; i < 16; ++i) {
    int orow = i * 4 + rr;
    float v = t[cc][orow];
    long oidx = zoff + (long)(c0 + orow) * R + r0 + cc;
    bf16 hi = (bf16)v;
    oh[oidx] = hi;
    if (SPLIT) ol[oidx] = (bf16)(v - (float)hi);
  }
}

// combine two fp32 partials -> bf16
__global__ void k_combine_bf16(const float* __restrict__ p0,
                               const float* __restrict__ p1,
                               bf16* __restrict__ o) {
  int i = blockIdx.x * 256 + threadIdx.x;
  f32x4 v = ((const f32x4*)p0)[i] + ((const f32x4*)p1)[i];
  bf16x4 ob;
#pragma unroll
  for (int j = 0; j < 4; ++j) ob[j] = (bf16)v[j];
  ((bf16x4*)o)[i] = ob;
}

// ---------------- m97 GEMM: C[M,N] = A[M,K] @ B[N,K]^T (R2-proven) --------
template <int EPI>
__global__ __launch_bounds__(256, 3) void k_gemm_bt(
    const bf16* __restrict__ A, const bf16* __restrict__ B,
    float* __restrict__ Cf, bf16* __restrict__ Cb,
    const float* __restrict__ bias, int M, int N, int K, int nsplit) {
  __shared__ bf16 sA[4096], sB[4096];
  const int tid = threadIdx.x, w = tid >> 6, l = tid & 63;
  const int l16 = l & 15, lg = l >> 4;
  const int wr = w >> 1, wc = w & 1;
  const long bm0 = (long)blockIdx.y * 128, bn0 = (long)blockIdx.x * 128;
  const int z = blockIdx.z;
  const int ks = K / nsplit, kbeg = z * ks, kend = kbeg + ks;
  float* Cfp = (Cf != nullptr) ? Cf + (long)z * M * N : nullptr;
  f32x4 acc[4][4];
#pragma unroll
  for (int m = 0; m < 4; ++m)
#pragma unroll
    for (int n = 0; n < 4; ++n)
#pragma unroll
      for (int j = 0; j < 4; ++j) acc[m][n][j] = 0.f;

  for (int kt = kbeg; kt < kend; kt += 32) {
    __syncthreads();
#pragma unroll
    for (int i = 0; i < 2; ++i) {
      int c = (w * 2 + i) * 64 + l;
      int row = c >> 2, seg = c & 3;
      cp16(&sA[(w * 2 + i) * 512], &A[(bm0 + row) * K + kt + seg * 8]);
      cp16(&sB[(w * 2 + i) * 512], &B[(bn0 + row) * K + kt + seg * 8]);
    }
    __syncthreads();
    bf16x8 a[4], b[4];
#pragma unroll
    for (int m = 0; m < 4; ++m)
      a[m] = *(const bf16x8*)&sA[(wr * 64 + m * 16 + l16) * 32 + lg * 8];
#pragma unroll
    for (int n = 0; n < 4; ++n)
      b[n] = *(const bf16x8*)&sB[(wc * 64 + n * 16 + l16) * 32 + lg * 8];
#pragma unroll
    for (int m = 0; m < 4; ++m)
#pragma unroll
      for (int n = 0; n < 4; ++n)
        acc[m][n] = MFMA(a[m], b[n], acc[m][n]);
  }
#pragma unroll
  for (int m = 0; m < 4; ++m)
#pragma unroll
    for (int n = 0; n < 4; ++n) {
      long col = bn0 + wc * 64 + n * 16 + l16;
      float bv = (bias != nullptr) ? bias[col] : 0.f;
#pragma unroll
      for (int j = 0; j < 4; ++j) {
        long row = bm0 + wr * 64 + m * 16 + lg * 4 + j;
        float v = acc[m][n][j];
        if (EPI == 0) {
          Cfp[row * N + col] = v + bv;
        } else {
          v = fmaxf(v + bv, 0.f);
          Cb[row * N + col] = (bf16)v;
        }
      }
    }
}

// ---------------- 8-phase 256^2 GEMM body (probe-only this round) ---------
template <int EPI>
__device__ __forceinline__ void gemm8_body(
    char* lds, const bf16* __restrict__ A, const bf16* __restrict__ B,
    float* __restrict__ Cf, bf16* __restrict__ Cb,
    const float* __restrict__ bias, int M, int N, int K, int nsplit) {
  const int tid = threadIdx.x, w = tid >> 6, l = tid & 63;
  const int l16 = l & 15, lg = l >> 4;
  const int wr = w >> 2, wc = w & 3;
  const long bm0 = (long)blockIdx.y * 256, bn0 = (long)blockIdx.x * 256;
  const int z = blockIdx.z;
  const int ksz = K / nsplit, kbeg = z * ksz;
  const int nt = ksz >> 6;
  const long lK = K;

  const int srow = w * 8 + (l >> 3);
  const int sslot = (l & 7) ^ (l >> 3);

  auto STAGE = [&](int bufp, int isB, int h, int tt) {
    int tc = tt < nt ? tt : nt - 1;
    char* dst = lds + bufp * 65536 + isB * 32768 + h * 16384 + w * 1024;
    const bf16* G = isB ? B : A;
    long r0 = (isB ? bn0 : bm0) + h * 128 + srow;
    const bf16* src = G + r0 * lK + kbeg + tc * 64 + sslot * 8;
    cp16(dst, src);
    cp16(dst + 8192, src + 64 * lK);
  };
  auto LDA = [&](int bufp, int mf, int ks) -> bf16x8 {
    int inrow = (mf & 3) * 32 + wr * 16 + l16;
    int byo = bufp * 65536 + (mf >> 2) * 16384 + inrow * 128 +
              ((((ks << 2) + lg) ^ (inrow & 7)) << 4);
    return *(const bf16x8*)(lds + byo);
  };
  auto LDB = [&](int bufp, int nf, int ks) -> bf16x8 {
    int inrow = (nf & 1) * 64 + wc * 16 + l16;
    int byo = bufp * 65536 + 32768 + (nf >> 1) * 16384 + inrow * 128 +
              ((((ks << 2) + lg) ^ (inrow & 7)) << 4);
    return *(const bf16x8*)(lds + byo);
  };

  f32x4 acc[8][4];
#pragma unroll
  for (int mf = 0; mf < 8; ++mf)
#pragma unroll
    for (int nf = 0; nf < 4; ++nf)
#pragma unroll
      for (int j = 0; j < 4; ++j) acc[mf][nf][j] = 0.f;

  STAGE(0, 0, 0, 0);
  STAGE(0, 1, 0, 0);
  STAGE(0, 0, 1, 0);
  STAGE(0, 1, 1, 0);
  STAGE(1, 1, 0, 1);
  STAGE(1, 0, 1, 1);
  STAGE(1, 1, 1, 1);
  SBAR();
  VMC6();
  GBAR();

  bf16x8 a[4][2], b[2][2];
  for (int t = 0; t < nt; ++t) {
    const int cb = t & 1, nb = cb ^ 1;
    // P1: A-h0 x B-h0 ; stage nb A-h0 (t+1)
#pragma unroll
    for (int mf = 0; mf < 4; ++mf)
#pragma unroll
      for (int ks = 0; ks < 2; ++ks) a[mf][ks] = LDA(cb, mf, ks);
#pragma unroll
    for (int nf = 0; nf < 2; ++nf)
#pragma unroll
      for (int ks = 0; ks < 2; ++ks) b[nf][ks] = LDB(cb, nf, ks);
    STAGE(nb, 0, 0, t + 1);
    SBAR();
    GBAR();
    LGKM0();
    __builtin_amdgcn_s_setprio(1);
#pragma unroll
    for (int mf = 0; mf < 4; ++mf)
#pragma unroll
      for (int nf = 0; nf < 2; ++nf)
#pragma unroll
        for (int ks = 0; ks < 2; ++ks)
          acc[mf][nf] = MFMA(a[mf][ks], b[nf][ks], acc[mf][nf]);
    __builtin_amdgcn_s_setprio(0);
    GBAR();
    // P2: A-h1 x B-h0 ; stage cb B-h0 (t+2)
#pragma unroll
    for (int mf = 0; mf < 4; ++mf)
#pragma unroll
      for (int ks = 0; ks < 2; ++ks) a[mf][ks] = LDA(cb, mf + 4, ks);
    STAGE(cb, 1, 0, t + 2);
    SBAR();
    GBAR();
    LGKM0();
    __builtin_amdgcn_s_setprio(1);
#pragma unroll
    for (int mf = 0; mf < 4; ++mf)
#pragma unroll
      for (int nf = 0; nf < 2; ++nf)
#pragma unroll
        for (int ks = 0; ks < 2; ++ks)
          acc[mf + 4][nf] = MFMA(a[mf][ks], b[nf][ks], acc[mf + 4][nf]);
    __builtin_amdgcn_s_setprio(0);
    GBAR();
    // P3: A-h1 x B-h1
#pragma unroll
    for (int nf = 0; nf < 2; ++nf)
#pragma unroll
      for (int ks = 0; ks < 2; ++ks) b[nf][ks] = LDB(cb, nf + 2, ks);
    GBAR();
    LGKM0();
    __builtin_amdgcn_s_setprio(1);
#pragma unroll
    for (int mf = 0; mf < 4; ++mf)
#pragma unroll
      for (int nf = 0; nf < 2; ++nf)
#pragma unroll
        for (int ks = 0; ks < 2; ++ks)
          acc[mf + 4][nf + 2] = MFMA(a[mf][ks], b[nf][ks], acc[mf + 4][nf + 2]);
    __builtin_amdgcn_s_setprio(0);
    GBAR();
    // P4: A-h0 x B-h1 ; stage cb A-h1,B-h1 (t+2) ; vmcnt(6)
#pragma unroll
    for (int mf = 0; mf < 4; ++mf)
#pragma unroll
      for (int ks = 0; ks < 2; ++ks) a[mf][ks] = LDA(cb, mf, ks);
    STAGE(cb, 0, 1, t + 2);
    STAGE(cb, 1, 1, t + 2);
    SBAR();
    VMC6();
    GBAR();
    LGKM0();
    __builtin_amdgcn_s_setprio(1);
#pragma unroll
    for (int mf = 0; mf < 4; ++mf)
#pragma unroll
      for (int nf = 0; nf < 2; ++nf)
#pragma unroll
        for (int ks = 0; ks < 2; ++ks)
          acc[mf][nf + 2] = MFMA(a[mf][ks], b[nf][ks], acc[mf][nf + 2]);
    __builtin_amdgcn_s_setprio(0);
    GBAR();
  }
  asm volatile("s_waitcnt vmcnt(0) lgkmcnt(0)" ::: "memory");

#pragma unroll
  for (int mf = 0; mf < 8; ++mf)
#pragma unroll
    for (int nf = 0; nf < 4; ++nf) {
      long col = bn0 + nf * 64 + wc * 16 + l16;
      float bv = (EPI == 2) ? bias[col] : 0.f;
#pragma unroll
      for (int jj = 0; jj < 4; ++jj) {
        long row = bm0 + mf * 32 + wr * 16 + lg * 4 + jj;
        float v = acc[mf][nf][jj];
        if (EPI == 0) {
          Cf[(long)z * M * N + row * N + col] = v;
        } else {
          v = fmaxf(v + bv, 0.f);
          Cb[row * N + col] = (bf16)v;
        }
      }
    }
}

template <int EPI>
__global__ __launch_bounds__(512, 1) void k_gemm8s(
    const bf16* __restrict__ A, const bf16* __restrict__ B,
    float* __restrict__ Cf, bf16* __restrict__ Cb,
    const float* __restrict__ bias, int M, int N, int K, int nsplit) {
  __shared__ char lds[131072];
  gemm8_body<EPI>(lds, A, B, Cf, Cb, bias, M, N, K, nsplit);
}

template <int EPI>
__global__ __launch_bounds__(512, 1) void k_gemm8d(
    const bf16* __restrict__ A, const bf16* __restrict__ B,
    float* __restrict__ Cf, bf16* __restrict__ Cb,
    const float* __restrict__ bias, int M, int N, int K, int nsplit) {
  extern __shared__ char lds[];
  gemm8_body<EPI>(lds, A, B, Cf, Cb, bias, M, N, K, nsplit);
}

// ---------------- split-precision GEMM (Q/K projection) ----------------
__global__ __launch_bounds__(256, 2) void k_gemm_split3(
    const bf16* __restrict__ Ah, const bf16* __restrict__ Al,
    const bf16* __restrict__ Bh, const bf16* __restrict__ Bl,
    bf16* __restrict__ Ch, bf16* __restrict__ Cl,
    int M, int N, int K, float scale, int scale_ncols) {
  __shared__ bf16 sAh[4096], sAl[4096], sBh[4096], sBl[4096];
  const int tid = threadIdx.x, w = tid >> 6, l = tid & 63;
  const int l16 = l & 15, lg = l >> 4;
  const int wr = w >> 1, wc = w & 1;
  const long bm0 = (long)blockIdx.y * 128, bn0 = (long)blockIdx.x * 128;
  f32x4 acc[4][4];
#pragma unroll
  for (int m = 0; m < 4; ++m)
#pragma unroll
    for (int n = 0; n < 4; ++n)
#pragma unroll
      for (int j = 0; j < 4; ++j) acc[m][n][j] = 0.f;

  for (int kt = 0; kt < K; kt += 32) {
    __syncthreads();
#pragma unroll
    for (int i = 0; i < 2; ++i) {
      int c = (w * 2 + i) * 64 + l;
      int row = c >> 2, seg = c & 3;
      long ao = (bm0 + row) * K + kt + seg * 8;
      long bo = (bn0 + row) * K + kt + seg * 8;
      int db = (w * 2 + i) * 512;
      cp16(&sAh[db], &Ah[ao]);
      cp16(&sAl[db], &Al[ao]);
      cp16(&sBh[db], &Bh[bo]);
      cp16(&sBl[db], &Bl[bo]);
    }
    __syncthreads();
    bf16x8 ah[4], al[4], bh[4], bl[4];
#pragma unroll
    for (int m = 0; m < 4; ++m) {
      int off = (wr * 64 + m * 16 + l16) * 32 + lg * 8;
      ah[m] = *(const bf16x8*)&sAh[off];
      al[m] = *(const bf16x8*)&sAl[off];
    }
#pragma unroll
    for (int n = 0; n < 4; ++n) {
      int off = (wc * 64 + n * 16 + l16) * 32 + lg * 8;
      bh[n] = *(const bf16x8*)&sBh[off];
      bl[n] = *(const bf16x8*)&sBl[off];
    }
#pragma unroll
    for (int m = 0; m < 4; ++m)
#pragma unroll
      for (int n = 0; n < 4; ++n) {
        acc[m][n] = MFMA(ah[m], bh[n], acc[m][n]);
        acc[m][n] = MFMA(ah[m], bl[n], acc[m][n]);
        acc[m][n] = MFMA(al[m], bh[n], acc[m][n]);
      }
  }
#pragma unroll
  for (int m = 0; m < 4; ++m)
#pragma unroll
    for (int n = 0; n < 4; ++n) {
      long col = bn0 + wc * 64 + n * 16 + l16;
      float sc = (col < scale_ncols) ? scale : 1.0f;
#pragma unroll
      for (int j = 0; j < 4; ++j) {
        long row = bm0 + wr * 64 + m * 16 + lg * 4 + j;
        float v = acc[m][n][j] * sc;
        bf16 hi = (bf16)v;
        Ch[row * N + col] = hi;
        Cl[row * N + col] = (bf16)(v - (float)hi);
      }
    }
}

// ---------------- flash attention (R2-exact) ----------------
__global__ __launch_bounds__(256, 2) void k_flash(
    const bf16* __restrict__ Qh, const bf16* __restrict__ Ql,
    const bf16* __restrict__ Kh, const bf16* __restrict__ Kl,
    const bf16* __restrict__ Vt, bf16* __restrict__ Oc) {
  __shared__ bf16 sm[28672];
  bf16* sKh = sm;
  bf16* sKl = sm + 8192;
  bf16* sVt = sm + 16384;
  bf16* sP = sm + 24576;
  const int tid = threadIdx.x, w = tid >> 6, l = tid & 63;
  const int l16 = l & 15, lg = l >> 4;
  const int head = blockIdx.y;
  const long q0 = (long)blockIdx.x * 64;

  bf16x8 qh_r[4], ql_r[4];
#pragma unroll
  for (int kk = 0; kk < 4; ++kk) {
    long off = (q0 + w * 16 + l16) * 4096 + head * 128 + kk * 32 + lg * 8;
    qh_r[kk] = *(const bf16x8*)&Qh[off];
    ql_r[kk] = *(const bf16x8*)&Ql[off];
  }

  f32x4 acc_o[8];
#pragma unroll
  for (int n = 0; n < 8; ++n)
#pragma unroll
    for (int j = 0; j < 4; ++j) acc_o[n][j] = 0.f;
  float mrow[4], lrow[4];
#pragma unroll
  for (int j = 0; j < 4; ++j) {
    mrow[j] = NEG_INF;
    lrow[j] = 0.f;
  }

  for (int t0 = 0; t0 < 2048; t0 += 64) {
    __syncthreads();
#pragma unroll
    for (int i = 0; i < 4; ++i) {
      int c = (w * 4 + i) * 64 + l;
      int rk = c >> 4, sk = (c & 15) ^ (rk & 7);
      long ko = (long)(t0 + rk) * 4096 + head * 128 + sk * 8;
      int db = (w * 4 + i) * 512;
      cp16(&sKh[db], &Kh[ko]);
      cp16(&sKl[db], &Kl[ko]);
      int rv = c >> 3, sv = (c & 7) ^ (rv & 7);
      long vo = (long)(head * 128 + rv) * 2048 + t0 + sv * 8;
      cp16(&sVt[db], &Vt[vo]);
    }
    __syncthreads();

    f32x4 s[4];
#pragma unroll
    for (int n = 0; n < 4; ++n)
#pragma unroll
      for (int j = 0; j < 4; ++j) s[n][j] = 0.f;
#pragma unroll
    for (int kk = 0; kk < 4; ++kk) {
      bf16x8 bh[4], bl[4];
#pragma unroll
      for (int n = 0; n < 4; ++n) {
        int r = n * 16 + l16;
        int byo = r * 256 + (((kk * 4 + lg) ^ (r & 7)) << 4);
        bh[n] = *(const bf16x8*)((const char*)sKh + byo);
        bl[n] = *(const bf16x8*)((const char*)sKl + byo);
      }
#pragma unroll
      for (int n = 0; n < 4; ++n) {
        s[n] = MFMA(qh_r[kk], bh[n], s[n]);
        s[n] = MFMA(qh_r[kk], bl[n], s[n]);
        s[n] = MFMA(ql_r[kk], bh[n], s[n]);
      }
    }

#pragma unroll
    for (int j = 0; j < 4; ++j) {
      float mx = fmaxf(fmaxf(s[0][j], s[1][j]), fmaxf(s[2][j], s[3][j]));
      mx = fmaxf(mx, __shfl_xor(mx, 1));
      mx = fmaxf(mx, __shfl_xor(mx, 2));
      mx = fmaxf(mx, __shfl_xor(mx, 4));
      mx = fmaxf(mx, __shfl_xor(mx, 8));
      float mo = mrow[j];
      float mn = fmaxf(mo, mx);
      mrow[j] = mn;
      float f = __expf(mo - mn);
      int prow = w * 16 + lg * 4 + j;
      float ssum = 0.f;
#pragma unroll
      for (int n = 0; n < 4; ++n) {
        float p = __expf(s[n][j] - mn);
        ssum += p;
        int byo = prow * 128 + (((n * 16 + l16) * 2) ^ ((prow & 7) << 4));
        *(bf16*)((char*)sP + byo) = (bf16)p;
      }
      ssum += __shfl_xor(ssum, 1);
      ssum += __shfl_xor(ssum, 2);
      ssum += __shfl_xor(ssum, 4);
      ssum += __shfl_xor(ssum, 8);
      lrow[j] = lrow[j] * f + ssum;
#pragma unroll
      for (int n = 0; n < 8; ++n) acc_o[n][j] *= f;
    }

#pragma unroll
    for (int kk = 0; kk < 2; ++kk) {
      bf16x8 pa, bv[8];
      {
        int r = w * 16 + l16;
        int byo = r * 128 + (((kk * 4 + lg) ^ (r & 7)) << 4);
        pa = *(const bf16x8*)((const char*)sP + byo);
      }
#pragma unroll
      for (int n = 0; n < 8; ++n) {
        int r = n * 16 + l16;
        int byo = r * 128 + (((kk * 4 + lg) ^ (r & 7)) << 4);
        bv[n] = *(const bf16x8*)((const char*)sVt + byo);
      }
#pragma unroll
      for (int n = 0; n < 8; ++n) acc_o[n] = MFMA(pa, bv[n], acc_o[n]);
    }
  }

#pragma unroll
  for (int j = 0; j < 4; ++j) {
    float rinv = 1.f / lrow[j];
    long row = q0 + w * 16 + lg * 4 + j;
#pragma unroll
    for (int n = 0; n < 8; ++n)
      Oc[row * 2048 + head * 128 + n * 16 + l16] = (bf16)(acc_o[n][j] * rinv);
  }
}

// ---------------- residual(+partials) + LayerNorm (R2-exact) --------------
__global__ __launch_bounds__(256) void k_add_ln(
    const float* __restrict__ a, const float* __restrict__ b,
    const float* __restrict__ c, const float* __restrict__ bias,
    const float* __restrict__ g, const float* __restrict__ be,
    float* __restrict__ o32, bf16* __restrict__ obf) {
  __shared__ float red[8];
  int row = blockIdx.x, tid = threadIdx.x;
  const float* pa = a + (long)row * 2048;
  const float* pb = b + (long)row * 2048;
  const float* pc = (c != nullptr) ? c + (long)row * 2048 : nullptr;
  f32x4 v[2];
  float sum = 0.f, sq = 0.f;
#pragma unroll
  for (int i = 0; i < 2; ++i) {
    int idx = i * 1024 + tid * 4;
    f32x4 va = *(const f32x4*)(pa + idx);
    f32x4 vb = *(const f32x4*)(pb + idx);
    v[i] = va + vb;
    if (pc != nullptr) v[i] += *(const f32x4*)(pc + idx);
    if (bias != nullptr) v[i] += *(const f32x4*)(bias + idx);
#pragma unroll
    for (int j = 0; j < 4; ++j) {
      sum += v[i][j];
      sq += v[i][j] * v[i][j];
    }
  }
#pragma unroll
  for (int o = 1; o < 64; o <<= 1) {
    sum += __shfl_xor(sum, o);
    sq += __shfl_xor(sq, o);
  }
  int w = tid >> 6;
  if ((tid & 63) == 0) {
    red[w * 2] = sum;
    red[w * 2 + 1] = sq;
  }
  __syncthreads();
  sum = red[0] + red[2] + red[4] + red[6];
  sq = red[1] + red[3] + red[5] + red[7];
  float mu = sum * (1.f / 2048.f);
  float var = sq * (1.f / 2048.f) - mu * mu;
  float rs = rsqrtf(var + 1e-5f);
#pragma unroll
  for (int i = 0; i < 2; ++i) {
    int idx = i * 1024 + tid * 4;
    f32x4 vg = *(const f32x4*)(g + idx);
    f32x4 vb = *(const f32x4*)(be + idx);
    f32x4 o;
#pragma unroll
    for (int j = 0; j < 4; ++j) o[j] = (v[i][j] - mu) * rs * vg[j] + vb[j];
    *(f32x4*)(o32 + (long)row * 2048 + idx) = o;
    if (obf != nullptr) {
      bf16x4 ob;
#pragma unroll
      for (int j = 0; j < 4; ++j) ob[j] = (bf16)o[j];
      *(bf16x4*)(obf + (long)row * 2048 + idx) = ob;
    }
  }
}

// ---------------- launch ----------------
extern "C" void kernel_launch(void* const* d_in, const int* in_sizes, int n_in,
                              void* d_out, int out_size, void* d_ws, size_t ws_size,
                              hipStream_t stream) {
  const float* x    = (const float*)d_in[0];
  const float* wq   = (const float*)d_in[1];
  const float* wk   = (const float*)d_in[2];
  const float* wv   = (const float*)d_in[3];
  const float* wp   = (const float*)d_in[4];
  const float* g1   = (const float*)d_in[5];
  const float* b1   = (const float*)d_in[6];
  const float* fc1w = (const float*)d_in[7];
  const float* fc1b = (const float*)d_in[8];
  const float* fc2w = (const float*)d_in[9];
  const float* fc2b = (const float*)d_in[10];
  const float* g2   = (const float*)d_in[11];
  const float* b2   = (const float*)d_in[12];
  float* out = (float*)d_out;

  char* ws = (char*)d_ws;
  const size_t MB = 1024 * 1024;
  if (ws_size < 216 * MB) return;

  bf16* xh   = (bf16*)(ws + 0 * MB);
  bf16* xl   = (bf16*)(ws + 8 * MB);
  bf16* wqh  = (bf16*)(ws + 16 * MB);
  bf16* wkh  = (bf16*)(ws + 24 * MB);
  bf16* wql  = (bf16*)(ws + 32 * MB);
  bf16* wkl  = (bf16*)(ws + 40 * MB);
  bf16* wvt  = (bf16*)(ws + 48 * MB);
  bf16* wpt  = (bf16*)(ws + 56 * MB);
  bf16* fc1t = (bf16*)(ws + 64 * MB);
  bf16* fc2t = (bf16*)(ws + 96 * MB);
  bf16* qkh  = (bf16*)(ws + 128 * MB);
  bf16* qkl  = (bf16*)(ws + 144 * MB);
  bf16* vt   = (bf16*)(ws + 160 * MB);
  bf16* cc   = (bf16*)(ws + 168 * MB);
  float* vtp  = (float*)(ws + 176 * MB);  // 2x16MB (also probe target)
  float* aop  = (float*)(ws + 128 * MB);
  float* ffp  = (float*)(ws + 0 * MB);
  float* h32  = (float*)(ws + 176 * MB);
  bf16*  hbf  = (bf16*)(ws + 192 * MB);
  bf16*  ff1  = (bf16*)(ws + 128 * MB);

  // converts
  k_split_x<<<4096, 256, 0, stream>>>(x, xh, xl);
  k_tcvt<true ><<<dim3(2, 32, 16), 256, 0, stream>>>(wq, wqh, wql, 2048, 128);
  k_tcvt<true ><<<dim3(2, 32, 16), 256, 0, stream>>>(wk, wkh, wkl, 2048, 128);
  k_tcvt<false><<<dim3(2, 32, 16), 256, 0, stream>>>(wv, wvt, nullptr, 2048, 128);
  k_tcvt<false><<<dim3(32, 32, 1), 256, 0, stream>>>(wp, wpt, nullptr, 2048, 2048);
  k_tcvt<false><<<dim3(128, 32, 1), 256, 0, stream>>>(fc1w, fc1t, nullptr, 2048, 8192);
  k_tcvt<false><<<dim3(32, 128, 1), 256, 0, stream>>>(fc2w, fc2t, nullptr, 8192, 2048);

  // fused Q,K projection (split3), 1/sqrt(128) folded into Q cols
  k_gemm_split3<<<dim3(32, 16), 256, 0, stream>>>(
      xh, xl, wqh, wql, qkh, qkl, 2048, 4096, 2048, 0.08838834764831845f, 2048);

  // ---- PROBES (dead output: vtp fully overwritten by real vt below) ----
  // probe A: static 128KB LDS (the R3/R4 launch config under suspicion)
  k_gemm8s<0><<<dim3(8, 8, 1), 512, 0, stream>>>(
      wvt, xh, vtp, nullptr, nullptr, 2048, 2048, 2048, 1);
  // probe B: dynamic 128KB LDS + opt-in attribute
  hipFuncSetAttribute(reinterpret_cast<const void*>(k_gemm8d<0>),
                      hipFuncAttributeMaxDynamicSharedMemorySize, 131072);
  k_gemm8d<0><<<dim3(8, 8, 1), 512, 131072, stream>>>(
      wvt, xh, vtp, nullptr, nullptr, 2048, 2048, 2048, 1);

  // V^T: real computation (m97 structure, split-K=2), overwrites probes
  k_gemm_bt<0><<<dim3(16, 16, 2), 256, 0, stream>>>(
      wvt, xh, vtp, nullptr, nullptr, 2048, 2048, 2048, 2);
  k_combine_bf16<<<4096, 256, 0, stream>>>(vtp, vtp + 4 * MB, vt);
  // attention -> concat
  k_flash<<<dim3(32, 16), 256, 0, stream>>>(qkh, qkl, qkh + 2048, qkl + 2048,
                                            vt, cc);
  // out projection, split-K=2 (partials combined inside LN1)
  k_gemm_bt<0><<<dim3(16, 16, 2), 256, 0, stream>>>(
      cc, wpt, aop, nullptr, nullptr, 2048, 2048, 2048, 2);
  // h = LN(x + p0 + p1)
  k_add_ln<<<2048, 256, 0, stream>>>(x, aop, aop + 4 * MB, nullptr, g1, b1,
                                     h32, hbf);
  // ff1 = relu(h @ fc1 + b1)
  k_gemm_bt<2><<<dim3(64, 16, 1), 256, 0, stream>>>(
      hbf, fc1t, nullptr, ff1, fc1b, 2048, 8192, 2048, 1);
  // ff2 partials, split-K=2 over K=8192
  k_gemm_bt<0><<<dim3(16, 16, 2), 256, 0, stream>>>(
      ff1, fc2t, ffp, nullptr, nullptr, 2048, 2048, 8192, 2);
  // out = LN(h + p0 + p1 + fc2b)
  k_add_ln<<<2048, 256, 0, stream>>>(h32, ffp, ffp + 4 * MB, fc2b, g2, b2,
                                     out, nullptr);
}

// Round 6
// 638.307 us; speedup vs baseline: 1.0729x; 1.0729x over previous
//
#include <hip/hip_runtime.h>

// TransformerBlock fused pipeline for MI355X (gfx950).
// SEQ=2048, D_MODEL=2048, H=16, DK=DV=128, DFF=8192. fp32 in/out.
//
// R6: R5-proven pipeline (m97 gemm_bt + split3 + flash + add_ln) + VALUE
// check of the 8-phase gemm8: gemm8 computes V^T into a dead buffer; k_vcheck
// compares vs the real vt and burns time ~ mismatch count. The k_vcheck
// dispatch duration in rocprof IS the verdict (~3us correct, >>50us wrong).
// R3/R4 failed with identical absmax across different schedules => shared
// deterministic wrong-output suspected in STAGE/LDA/LDB addressing; R5
// proved launches work but discarded outputs.

typedef __bf16 bf16;
typedef __attribute__((ext_vector_type(8))) __bf16 bf16x8;
typedef __attribute__((ext_vector_type(4))) __bf16 bf16x4;
typedef __attribute__((ext_vector_type(4))) float f32x4;

#define MFMA(a, b, c) __builtin_amdgcn_mfma_f32_16x16x32_bf16((a), (b), (c), 0, 0, 0)
#define NEG_INF (-3.402823466e38f)

__device__ __forceinline__ void cp16(void* lds, const void* g) {
  __builtin_amdgcn_global_load_lds(
      (const __attribute__((address_space(1))) unsigned int*)g,
      (__attribute__((address_space(3))) unsigned int*)lds, 16, 0, 0);
}

#define SBAR() __builtin_amdgcn_sched_barrier(0)
#define GBAR()                              \
  do {                                      \
    asm volatile("" ::: "memory");          \
    __builtin_amdgcn_s_barrier();           \
    asm volatile("" ::: "memory");          \
  } while (0)
#define LGKM0()                                         \
  do {                                                  \
    asm volatile("s_waitcnt lgkmcnt(0)" ::: "memory");  \
    __builtin_amdgcn_sched_barrier(0);                  \
  } while (0)
#define VMC6()                                          \
  do {                                                  \
    asm volatile("s_waitcnt vmcnt(6)" ::: "memory");    \
    __builtin_amdgcn_sched_barrier(0);                  \
  } while (0)

// ---------------- converts ----------------

__global__ void k_split_x(const float* __restrict__ x, bf16* __restrict__ xh,
                          bf16* __restrict__ xl) {
  int i = blockIdx.x * 256 + threadIdx.x;
  f32x4 v = ((const f32x4*)x)[i];
  bf16x4 h, l;
#pragma unroll
  for (int j = 0; j < 4; ++j) {
    bf16 hi = (bf16)v[j];
    h[j] = hi;
    l[j] = (bf16)(v[j] - (float)hi);
  }
  ((bf16x4*)xh)[i] = h;
  ((bf16x4*)xl)[i] = l;
}

template <bool SPLIT>
__global__ void k_tcvt(const float* __restrict__ in, bf16* __restrict__ oh,
                       bf16* __restrict__ ol, int R, int C) {
  __shared__ float t[64][65];
  long zoff = (long)blockIdx.z * R * C;
  int c0 = blockIdx.x * 64, r0 = blockIdx.y * 64;
  int cc = threadIdx.x & 63, rr = threadIdx.x >> 6;
#pragma unroll
  for (int i = 0; i < 16; ++i) {
    int r = i * 4 + rr;
    t[r][cc] = in[zoff + (long)(r0 + r) * C + c0 + cc];
  }
  __syncthreads();
#pragma unroll
  for (int i = 0; i < 16; ++i) {
    int orow = i * 4 + rr;
    float v = t[cc][orow];
    long oidx = zoff + (long)(c0 + orow) * R + r0 + cc;
    bf16 hi = (bf16)v;
    oh[oidx] = hi;
    if (SPLIT) ol[oidx] = (bf16)(v - (float)hi);
  }
}

// combine two fp32 partials -> bf16
__global__ void k_combine_bf16(const float* __restrict__ p0,
                               const float* __restrict__ p1,
                               bf16* __restrict__ o) {
  int i = blockIdx.x * 256 + threadIdx.x;
  f32x4 v = ((const f32x4*)p0)[i] + ((const f32x4*)p1)[i];
  bf16x4 ob;
#pragma unroll
  for (int j = 0; j < 4; ++j) ob[j] = (bf16)v[j];
  ((bf16x4*)o)[i] = ob;
}

// ---------------- value-check with timing side channel ----------------
// dur_us ~ 2-4us if a matches b everywhere (|diff|<=tol); grows ~7us per
// mismatch/thread (max 16/thread -> ~110us). Deterministic.
__global__ void k_vcheck(const float* __restrict__ a, const bf16* __restrict__ b,
                         float tol, long n) {
  long i0 = (long)blockIdx.x * 256 + threadIdx.x;
  int cnt = 0;
  for (long i = i0; i < n; i += 262144L) {
    float d = a[i] - (float)b[i];
    if (fabsf(d) > tol) ++cnt;
  }
  float acc = 1.0f;
  int iters = cnt * 4096;
  for (int k = 0; k < iters; ++k) acc = fmaf(acc, 1.0000001f, 1e-7f);
  asm volatile("" ::"v"(acc));
}

// ---------------- m97 GEMM: C[M,N] = A[M,K] @ B[N,K]^T (proven) ----------
template <int EPI>
__global__ __launch_bounds__(256, 3) void k_gemm_bt(
    const bf16* __restrict__ A, const bf16* __restrict__ B,
    float* __restrict__ Cf, bf16* __restrict__ Cb,
    const float* __restrict__ bias, int M, int N, int K, int nsplit) {
  __shared__ bf16 sA[4096], sB[4096];
  const int tid = threadIdx.x, w = tid >> 6, l = tid & 63;
  const int l16 = l & 15, lg = l >> 4;
  const int wr = w >> 1, wc = w & 1;
  const long bm0 = (long)blockIdx.y * 128, bn0 = (long)blockIdx.x * 128;
  const int z = blockIdx.z;
  const int ks = K / nsplit, kbeg = z * ks, kend = kbeg + ks;
  float* Cfp = (Cf != nullptr) ? Cf + (long)z * M * N : nullptr;
  f32x4 acc[4][4];
#pragma unroll
  for (int m = 0; m < 4; ++m)
#pragma unroll
    for (int n = 0; n < 4; ++n)
#pragma unroll
      for (int j = 0; j < 4; ++j) acc[m][n][j] = 0.f;

  for (int kt = kbeg; kt < kend; kt += 32) {
    __syncthreads();
#pragma unroll
    for (int i = 0; i < 2; ++i) {
      int c = (w * 2 + i) * 64 + l;
      int row = c >> 2, seg = c & 3;
      cp16(&sA[(w * 2 + i) * 512], &A[(bm0 + row) * K + kt + seg * 8]);
      cp16(&sB[(w * 2 + i) * 512], &B[(bn0 + row) * K + kt + seg * 8]);
    }
    __syncthreads();
    bf16x8 a[4], b[4];
#pragma unroll
    for (int m = 0; m < 4; ++m)
      a[m] = *(const bf16x8*)&sA[(wr * 64 + m * 16 + l16) * 32 + lg * 8];
#pragma unroll
    for (int n = 0; n < 4; ++n)
      b[n] = *(const bf16x8*)&sB[(wc * 64 + n * 16 + l16) * 32 + lg * 8];
#pragma unroll
    for (int m = 0; m < 4; ++m)
#pragma unroll
      for (int n = 0; n < 4; ++n)
        acc[m][n] = MFMA(a[m], b[n], acc[m][n]);
  }
#pragma unroll
  for (int m = 0; m < 4; ++m)
#pragma unroll
    for (int n = 0; n < 4; ++n) {
      long col = bn0 + wc * 64 + n * 16 + l16;
      float bv = (bias != nullptr) ? bias[col] : 0.f;
#pragma unroll
      for (int j = 0; j < 4; ++j) {
        long row = bm0 + wr * 64 + m * 16 + lg * 4 + j;
        float v = acc[m][n][j];
        if (EPI == 0) {
          Cfp[row * N + col] = v + bv;
        } else {
          v = fmaxf(v + bv, 0.f);
          Cb[row * N + col] = (bf16)v;
        }
      }
    }
}

// ---------------- 8-phase 256^2 GEMM (under test; dead output) -------------
template <int EPI>
__global__ __launch_bounds__(512, 1) void k_gemm8s(
    const bf16* __restrict__ A, const bf16* __restrict__ B,
    float* __restrict__ Cf, bf16* __restrict__ Cb,
    const float* __restrict__ bias, int M, int N, int K, int nsplit) {
  __shared__ char lds[131072];
  const int tid = threadIdx.x, w = tid >> 6, l = tid & 63;
  const int l16 = l & 15, lg = l >> 4;
  const int wr = w >> 2, wc = w & 3;
  const long bm0 = (long)blockIdx.y * 256, bn0 = (long)blockIdx.x * 256;
  const int z = blockIdx.z;
  const int ksz = K / nsplit, kbeg = z * ksz;
  const int nt = ksz >> 6;
  const long lK = K;

  const int srow = w * 8 + (l >> 3);
  const int sslot = (l & 7) ^ (l >> 3);

  auto STAGE = [&](int bufp, int isB, int h, int tt) {
    int tc = tt < nt ? tt : nt - 1;
    char* dst = lds + bufp * 65536 + isB * 32768 + h * 16384 + w * 1024;
    const bf16* G = isB ? B : A;
    long r0 = (isB ? bn0 : bm0) + h * 128 + srow;
    const bf16* src = G + r0 * lK + kbeg + tc * 64 + sslot * 8;
    cp16(dst, src);
    cp16(dst + 8192, src + 64 * lK);
  };
  auto LDA = [&](int bufp, int mf, int ks) -> bf16x8 {
    int inrow = (mf & 3) * 32 + wr * 16 + l16;
    int byo = bufp * 65536 + (mf >> 2) * 16384 + inrow * 128 +
              ((((ks << 2) + lg) ^ (inrow & 7)) << 4);
    return *(const bf16x8*)(lds + byo);
  };
  auto LDB = [&](int bufp, int nf, int ks) -> bf16x8 {
    int inrow = (nf & 1) * 64 + wc * 16 + l16;
    int byo = bufp * 65536 + 32768 + (nf >> 1) * 16384 + inrow * 128 +
              ((((ks << 2) + lg) ^ (inrow & 7)) << 4);
    return *(const bf16x8*)(lds + byo);
  };

  f32x4 acc[8][4];
#pragma unroll
  for (int mf = 0; mf < 8; ++mf)
#pragma unroll
    for (int nf = 0; nf < 4; ++nf)
#pragma unroll
      for (int j = 0; j < 4; ++j) acc[mf][nf][j] = 0.f;

  STAGE(0, 0, 0, 0);
  STAGE(0, 1, 0, 0);
  STAGE(0, 0, 1, 0);
  STAGE(0, 1, 1, 0);
  STAGE(1, 1, 0, 1);
  STAGE(1, 0, 1, 1);
  STAGE(1, 1, 1, 1);
  SBAR();
  VMC6();
  GBAR();

  bf16x8 a[4][2], b[2][2];
  for (int t = 0; t < nt; ++t) {
    const int cb = t & 1, nb = cb ^ 1;
    // P1: A-h0 x B-h0 ; stage nb A-h0 (t+1)
#pragma unroll
    for (int mf = 0; mf < 4; ++mf)
#pragma unroll
      for (int ks = 0; ks < 2; ++ks) a[mf][ks] = LDA(cb, mf, ks);
#pragma unroll
    for (int nf = 0; nf < 2; ++nf)
#pragma unroll
      for (int ks = 0; ks < 2; ++ks) b[nf][ks] = LDB(cb, nf, ks);
    STAGE(nb, 0, 0, t + 1);
    SBAR();
    GBAR();
    LGKM0();
    __builtin_amdgcn_s_setprio(1);
#pragma unroll
    for (int mf = 0; mf < 4; ++mf)
#pragma unroll
      for (int nf = 0; nf < 2; ++nf)
#pragma unroll
        for (int ks = 0; ks < 2; ++ks)
          acc[mf][nf] = MFMA(a[mf][ks], b[nf][ks], acc[mf][nf]);
    __builtin_amdgcn_s_setprio(0);
    GBAR();
    // P2: A-h1 x B-h0 ; stage cb B-h0 (t+2)
#pragma unroll
    for (int mf = 0; mf < 4; ++mf)
#pragma unroll
      for (int ks = 0; ks < 2; ++ks) a[mf][ks] = LDA(cb, mf + 4, ks);
    STAGE(cb, 1, 0, t + 2);
    SBAR();
    GBAR();
    LGKM0();
    __builtin_amdgcn_s_setprio(1);
#pragma unroll
    for (int mf = 0; mf < 4; ++mf)
#pragma unroll
      for (int nf = 0; nf < 2; ++nf)
#pragma unroll
        for (int ks = 0; ks < 2; ++ks)
          acc[mf + 4][nf] = MFMA(a[mf][ks], b[nf][ks], acc[mf + 4][nf]);
    __builtin_amdgcn_s_setprio(0);
    GBAR();
    // P3: A-h1 x B-h1
#pragma unroll
    for (int nf = 0; nf < 2; ++nf)
#pragma unroll
      for (int ks = 0; ks < 2; ++ks) b[nf][ks] = LDB(cb, nf + 2, ks);
    GBAR();
    LGKM0();
    __builtin_amdgcn_s_setprio(1);
#pragma unroll
    for (int mf = 0; mf < 4; ++mf)
#pragma unroll
      for (int nf = 0; nf < 2; ++nf)
#pragma unroll
        for (int ks = 0; ks < 2; ++ks)
          acc[mf + 4][nf + 2] = MFMA(a[mf][ks], b[nf][ks], acc[mf + 4][nf + 2]);
    __builtin_amdgcn_s_setprio(0);
    GBAR();
    // P4: A-h0 x B-h1 ; stage cb A-h1,B-h1 (t+2) ; vmcnt(6)
#pragma unroll
    for (int mf = 0; mf < 4; ++mf)
#pragma unroll
      for (int ks = 0; ks < 2; ++ks) a[mf][ks] = LDA(cb, mf, ks);
    STAGE(cb, 0, 1, t + 2);
    STAGE(cb, 1, 1, t + 2);
    SBAR();
    VMC6();
    GBAR();
    LGKM0();
    __builtin_amdgcn_s_setprio(1);
#pragma unroll
    for (int mf = 0; mf < 4; ++mf)
#pragma unroll
      for (int nf = 0; nf < 2; ++nf)
#pragma unroll
        for (int ks = 0; ks < 2; ++ks)
          acc[mf][nf + 2] = MFMA(a[mf][ks], b[nf][ks], acc[mf][nf + 2]);
    __builtin_amdgcn_s_setprio(0);
    GBAR();
  }
  asm volatile("s_waitcnt vmcnt(0) lgkmcnt(0)" ::: "memory");

#pragma unroll
  for (int mf = 0; mf < 8; ++mf)
#pragma unroll
    for (int nf = 0; nf < 4; ++nf) {
      long col = bn0 + nf * 64 + wc * 16 + l16;
      float bv = (EPI == 2) ? bias[col] : 0.f;
#pragma unroll
      for (int jj = 0; jj < 4; ++jj) {
        long row = bm0 + mf * 32 + wr * 16 + lg * 4 + jj;
        float v = acc[mf][nf][jj];
        if (EPI == 0) {
          Cf[(long)z * M * N + row * N + col] = v;
        } else {
          v = fmaxf(v + bv, 0.f);
          Cb[row * N + col] = (bf16)v;
        }
      }
    }
}

// ---------------- split-precision GEMM (Q/K projection) ----------------
__global__ __launch_bounds__(256, 2) void k_gemm_split3(
    const bf16* __restrict__ Ah, const bf16* __restrict__ Al,
    const bf16* __restrict__ Bh, const bf16* __restrict__ Bl,
    bf16* __restrict__ Ch, bf16* __restrict__ Cl,
    int M, int N, int K, float scale, int scale_ncols) {
  __shared__ bf16 sAh[4096], sAl[4096], sBh[4096], sBl[4096];
  const int tid = threadIdx.x, w = tid >> 6, l = tid & 63;
  const int l16 = l & 15, lg = l >> 4;
  const int wr = w >> 1, wc = w & 1;
  const long bm0 = (long)blockIdx.y * 128, bn0 = (long)blockIdx.x * 128;
  f32x4 acc[4][4];
#pragma unroll
  for (int m = 0; m < 4; ++m)
#pragma unroll
    for (int n = 0; n < 4; ++n)
#pragma unroll
      for (int j = 0; j < 4; ++j) acc[m][n][j] = 0.f;

  for (int kt = 0; kt < K; kt += 32) {
    __syncthreads();
#pragma unroll
    for (int i = 0; i < 2; ++i) {
      int c = (w * 2 + i) * 64 + l;
      int row = c >> 2, seg = c & 3;
      long ao = (bm0 + row) * K + kt + seg * 8;
      long bo = (bn0 + row) * K + kt + seg * 8;
      int db = (w * 2 + i) * 512;
      cp16(&sAh[db], &Ah[ao]);
      cp16(&sAl[db], &Al[ao]);
      cp16(&sBh[db], &Bh[bo]);
      cp16(&sBl[db], &Bl[bo]);
    }
    __syncthreads();
    bf16x8 ah[4], al[4], bh[4], bl[4];
#pragma unroll
    for (int m = 0; m < 4; ++m) {
      int off = (wr * 64 + m * 16 + l16) * 32 + lg * 8;
      ah[m] = *(const bf16x8*)&sAh[off];
      al[m] = *(const bf16x8*)&sAl[off];
    }
#pragma unroll
    for (int n = 0; n < 4; ++n) {
      int off = (wc * 64 + n * 16 + l16) * 32 + lg * 8;
      bh[n] = *(const bf16x8*)&sBh[off];
      bl[n] = *(const bf16x8*)&sBl[off];
    }
#pragma unroll
    for (int m = 0; m < 4; ++m)
#pragma unroll
      for (int n = 0; n < 4; ++n) {
        acc[m][n] = MFMA(ah[m], bh[n], acc[m][n]);
        acc[m][n] = MFMA(ah[m], bl[n], acc[m][n]);
        acc[m][n] = MFMA(al[m], bh[n], acc[m][n]);
      }
  }
#pragma unroll
  for (int m = 0; m < 4; ++m)
#pragma unroll
    for (int n = 0; n < 4; ++n) {
      long col = bn0 + wc * 64 + n * 16 + l16;
      float sc = (col < scale_ncols) ? scale : 1.0f;
#pragma unroll
      for (int j = 0; j < 4; ++j) {
        long row = bm0 + wr * 64 + m * 16 + lg * 4 + j;
        float v = acc[m][n][j] * sc;
        bf16 hi = (bf16)v;
        Ch[row * N + col] = hi;
        Cl[row * N + col] = (bf16)(v - (float)hi);
      }
    }
}

// ---------------- flash attention (R2-exact) ----------------
__global__ __launch_bounds__(256, 2) void k_flash(
    const bf16* __restrict__ Qh, const bf16* __restrict__ Ql,
    const bf16* __restrict__ Kh, const bf16* __restrict__ Kl,
    const bf16* __restrict__ Vt, bf16* __restrict__ Oc) {
  __shared__ bf16 sm[28672];
  bf16* sKh = sm;
  bf16* sKl = sm + 8192;
  bf16* sVt = sm + 16384;
  bf16* sP = sm + 24576;
  const int tid = threadIdx.x, w = tid >> 6, l = tid & 63;
  const int l16 = l & 15, lg = l >> 4;
  const int head = blockIdx.y;
  const long q0 = (long)blockIdx.x * 64;

  bf16x8 qh_r[4], ql_r[4];
#pragma unroll
  for (int kk = 0; kk < 4; ++kk) {
    long off = (q0 + w * 16 + l16) * 4096 + head * 128 + kk * 32 + lg * 8;
    qh_r[kk] = *(const bf16x8*)&Qh[off];
    ql_r[kk] = *(const bf16x8*)&Ql[off];
  }

  f32x4 acc_o[8];
#pragma unroll
  for (int n = 0; n < 8; ++n)
#pragma unroll
    for (int j = 0; j < 4; ++j) acc_o[n][j] = 0.f;
  float mrow[4], lrow[4];
#pragma unroll
  for (int j = 0; j < 4; ++j) {
    mrow[j] = NEG_INF;
    lrow[j] = 0.f;
  }

  for (int t0 = 0; t0 < 2048; t0 += 64) {
    __syncthreads();
#pragma unroll
    for (int i = 0; i < 4; ++i) {
      int c = (w * 4 + i) * 64 + l;
      int rk = c >> 4, sk = (c & 15) ^ (rk & 7);
      long ko = (long)(t0 + rk) * 4096 + head * 128 + sk * 8;
      int db = (w * 4 + i) * 512;
      cp16(&sKh[db], &Kh[ko]);
      cp16(&sKl[db], &Kl[ko]);
      int rv = c >> 3, sv = (c & 7) ^ (rv & 7);
      long vo = (long)(head * 128 + rv) * 2048 + t0 + sv * 8;
      cp16(&sVt[db], &Vt[vo]);
    }
    __syncthreads();

    f32x4 s[4];
#pragma unroll
    for (int n = 0; n < 4; ++n)
#pragma unroll
      for (int j = 0; j < 4; ++j) s[n][j] = 0.f;
#pragma unroll
    for (int kk = 0; kk < 4; ++kk) {
      bf16x8 bh[4], bl[4];
#pragma unroll
      for (int n = 0; n < 4; ++n) {
        int r = n * 16 + l16;
        int byo = r * 256 + (((kk * 4 + lg) ^ (r & 7)) << 4);
        bh[n] = *(const bf16x8*)((const char*)sKh + byo);
        bl[n] = *(const bf16x8*)((const char*)sKl + byo);
      }
#pragma unroll
      for (int n = 0; n < 4; ++n) {
        s[n] = MFMA(qh_r[kk], bh[n], s[n]);
        s[n] = MFMA(qh_r[kk], bl[n], s[n]);
        s[n] = MFMA(ql_r[kk], bh[n], s[n]);
      }
    }

#pragma unroll
    for (int j = 0; j < 4; ++j) {
      float mx = fmaxf(fmaxf(s[0][j], s[1][j]), fmaxf(s[2][j], s[3][j]));
      mx = fmaxf(mx, __shfl_xor(mx, 1));
      mx = fmaxf(mx, __shfl_xor(mx, 2));
      mx = fmaxf(mx, __shfl_xor(mx, 4));
      mx = fmaxf(mx, __shfl_xor(mx, 8));
      float mo = mrow[j];
      float mn = fmaxf(mo, mx);
      mrow[j] = mn;
      float f = __expf(mo - mn);
      int prow = w * 16 + lg * 4 + j;
      float ssum = 0.f;
#pragma unroll
      for (int n = 0; n < 4; ++n) {
        float p = __expf(s[n][j] - mn);
        ssum += p;
        int byo = prow * 128 + (((n * 16 + l16) * 2) ^ ((prow & 7) << 4));
        *(bf16*)((char*)sP + byo) = (bf16)p;
      }
      ssum += __shfl_xor(ssum, 1);
      ssum += __shfl_xor(ssum, 2);
      ssum += __shfl_xor(ssum, 4);
      ssum += __shfl_xor(ssum, 8);
      lrow[j] = lrow[j] * f + ssum;
#pragma unroll
      for (int n = 0; n < 8; ++n) acc_o[n][j] *= f;
    }

#pragma unroll
    for (int kk = 0; kk < 2; ++kk) {
      bf16x8 pa, bv[8];
      {
        int r = w * 16 + l16;
        int byo = r * 128 + (((kk * 4 + lg) ^ (r & 7)) << 4);
        pa = *(const bf16x8*)((const char*)sP + byo);
      }
#pragma unroll
      for (int n = 0; n < 8; ++n) {
        int r = n * 16 + l16;
        int byo = r * 128 + (((kk * 4 + lg) ^ (r & 7)) << 4);
        bv[n] = *(const bf16x8*)((const char*)sVt + byo);
      }
#pragma unroll
      for (int n = 0; n < 8; ++n) acc_o[n] = MFMA(pa, bv[n], acc_o[n]);
    }
  }

#pragma unroll
  for (int j = 0; j < 4; ++j) {
    float rinv = 1.f / lrow[j];
    long row = q0 + w * 16 + lg * 4 + j;
#pragma unroll
    for (int n = 0; n < 8; ++n)
      Oc[row * 2048 + head * 128 + n * 16 + l16] = (bf16)(acc_o[n][j] * rinv);
  }
}

// ---------------- residual(+partials) + LayerNorm (proven) ----------------
__global__ __launch_bounds__(256) void k_add_ln(
    const float* __restrict__ a, const float* __restrict__ b,
    const float* __restrict__ c, const float* __restrict__ bias,
    const float* __restrict__ g, const float* __restrict__ be,
    float* __restrict__ o32, bf16* __restrict__ obf) {
  __shared__ float red[8];
  int row = blockIdx.x, tid = threadIdx.x;
  const float* pa = a + (long)row * 2048;
  const float* pb = b + (long)row * 2048;
  const float* pc = (c != nullptr) ? c + (long)row * 2048 : nullptr;
  f32x4 v[2];
  float sum = 0.f, sq = 0.f;
#pragma unroll
  for (int i = 0; i < 2; ++i) {
    int idx = i * 1024 + tid * 4;
    f32x4 va = *(const f32x4*)(pa + idx);
    f32x4 vb = *(const f32x4*)(pb + idx);
    v[i] = va + vb;
    if (pc != nullptr) v[i] += *(const f32x4*)(pc + idx);
    if (bias != nullptr) v[i] += *(const f32x4*)(bias + idx);
#pragma unroll
    for (int j = 0; j < 4; ++j) {
      sum += v[i][j];
      sq += v[i][j] * v[i][j];
    }
  }
#pragma unroll
  for (int o = 1; o < 64; o <<= 1) {
    sum += __shfl_xor(sum, o);
    sq += __shfl_xor(sq, o);
  }
  int w = tid >> 6;
  if ((tid & 63) == 0) {
    red[w * 2] = sum;
    red[w * 2 + 1] = sq;
  }
  __syncthreads();
  sum = red[0] + red[2] + red[4] + red[6];
  sq = red[1] + red[3] + red[5] + red[7];
  float mu = sum * (1.f / 2048.f);
  float var = sq * (1.f / 2048.f) - mu * mu;
  float rs = rsqrtf(var + 1e-5f);
#pragma unroll
  for (int i = 0; i < 2; ++i) {
    int idx = i * 1024 + tid * 4;
    f32x4 vg = *(const f32x4*)(g + idx);
    f32x4 vb = *(const f32x4*)(be + idx);
    f32x4 o;
#pragma unroll
    for (int j = 0; j < 4; ++j) o[j] = (v[i][j] - mu) * rs * vg[j] + vb[j];
    *(f32x4*)(o32 + (long)row * 2048 + idx) = o;
    if (obf != nullptr) {
      bf16x4 ob;
#pragma unroll
      for (int j = 0; j < 4; ++j) ob[j] = (bf16)o[j];
      *(bf16x4*)(obf + (long)row * 2048 + idx) = ob;
    }
  }
}

// ---------------- launch ----------------
extern "C" void kernel_launch(void* const* d_in, const int* in_sizes, int n_in,
                              void* d_out, int out_size, void* d_ws, size_t ws_size,
                              hipStream_t stream) {
  const float* x    = (const float*)d_in[0];
  const float* wq   = (const float*)d_in[1];
  const float* wk   = (const float*)d_in[2];
  const float* wv   = (const float*)d_in[3];
  const float* wp   = (const float*)d_in[4];
  const float* g1   = (const float*)d_in[5];
  const float* b1   = (const float*)d_in[6];
  const float* fc1w = (const float*)d_in[7];
  const float* fc1b = (const float*)d_in[8];
  const float* fc2w = (const float*)d_in[9];
  const float* fc2b = (const float*)d_in[10];
  const float* g2   = (const float*)d_in[11];
  const float* b2   = (const float*)d_in[12];
  float* out = (float*)d_out;

  char* ws = (char*)d_ws;
  const size_t MB = 1024 * 1024;
  if (ws_size < 216 * MB) return;

  bf16* xh   = (bf16*)(ws + 0 * MB);
  bf16* xl   = (bf16*)(ws + 8 * MB);
  bf16* wqh  = (bf16*)(ws + 16 * MB);
  bf16* wkh  = (bf16*)(ws + 24 * MB);
  bf16* wql  = (bf16*)(ws + 32 * MB);
  bf16* wkl  = (bf16*)(ws + 40 * MB);
  bf16* wvt  = (bf16*)(ws + 48 * MB);
  bf16* wpt  = (bf16*)(ws + 56 * MB);
  bf16* fc1t = (bf16*)(ws + 64 * MB);
  bf16* fc2t = (bf16*)(ws + 96 * MB);
  // dynamics (time-multiplexed):
  float* vtp  = (float*)(ws + 128 * MB);  // 2x16MB vt partials   [dies at combine]
  bf16* vt    = (bf16*)(ws + 160 * MB);   // 8MB
  float* vtp8 = (float*)(ws + 176 * MB);  // 16MB gemm8-under-test [dies before LN1]
  bf16* qkh   = (bf16*)(ws + 128 * MB);   // 16MB (after vtp dead)
  bf16* qkl   = (bf16*)(ws + 144 * MB);   // 16MB
  bf16* cc    = (bf16*)(ws + 168 * MB);   // 8MB
  float* aop  = (float*)(ws + 128 * MB);  // 2x16MB (after qk dead)
  float* h32  = (float*)(ws + 176 * MB);  // 16MB (after vtp8 dead)
  bf16*  hbf  = (bf16*)(ws + 192 * MB);   // 8MB
  bf16*  ff1  = (bf16*)(ws + 128 * MB);   // 32MB (after aop dead)
  float* ffp  = (float*)(ws + 0 * MB);    // 2x16MB (after x*/w* dead)

  // converts
  k_split_x<<<4096, 256, 0, stream>>>(x, xh, xl);
  k_tcvt<true ><<<dim3(2, 32, 16), 256, 0, stream>>>(wq, wqh, wql, 2048, 128);
  k_tcvt<true ><<<dim3(2, 32, 16), 256, 0, stream>>>(wk, wkh, wkl, 2048, 128);
  k_tcvt<false><<<dim3(2, 32, 16), 256, 0, stream>>>(wv, wvt, nullptr, 2048, 128);
  k_tcvt<false><<<dim3(32, 32, 1), 256, 0, stream>>>(wp, wpt, nullptr, 2048, 2048);
  k_tcvt<false><<<dim3(128, 32, 1), 256, 0, stream>>>(fc1w, fc1t, nullptr, 2048, 8192);
  k_tcvt<false><<<dim3(32, 128, 1), 256, 0, stream>>>(fc2w, fc2t, nullptr, 8192, 2048);

  // V^T real (m97, split-K=2) -> vt bf16
  k_gemm_bt<0><<<dim3(16, 16, 2), 256, 0, stream>>>(
      wvt, xh, vtp, nullptr, nullptr, 2048, 2048, 2048, 2);
  k_combine_bf16<<<4096, 256, 0, stream>>>(vtp, vtp + 4 * MB, vt);
  // V^T via gemm8 (under test) -> vtp8 (dead); then timing-side-channel check
  k_gemm8s<0><<<dim3(8, 8, 1), 512, 0, stream>>>(
      wvt, xh, vtp8, nullptr, nullptr, 2048, 2048, 2048, 1);
  k_vcheck<<<1024, 256, 0, stream>>>(vtp8, vt, 4.0f, 2048L * 2048);

  // fused Q,K projection (split3)
  k_gemm_split3<<<dim3(32, 16), 256, 0, stream>>>(
      xh, xl, wqh, wql, qkh, qkl, 2048, 4096, 2048, 0.08838834764831845f, 2048);
  // attention -> concat
  k_flash<<<dim3(32, 16), 256, 0, stream>>>(qkh, qkl, qkh + 2048, qkl + 2048,
                                            vt, cc);
  // out projection, split-K=2
  k_gemm_bt<0><<<dim3(16, 16, 2), 256, 0, stream>>>(
      cc, wpt, aop, nullptr, nullptr, 2048, 2048, 2048, 2);
  // h = LN(x + p0 + p1)
  k_add_ln<<<2048, 256, 0, stream>>>(x, aop, aop + 4 * MB, nullptr, g1, b1,
                                     h32, hbf);
  // ff1 = relu(h @ fc1 + b1)
  k_gemm_bt<2><<<dim3(64, 16, 1), 256, 0, stream>>>(
      hbf, fc1t, nullptr, ff1, fc1b, 2048, 8192, 2048, 1);
  // ff2 partials, split-K=2 over K=8192
  k_gemm_bt<0><<<dim3(16, 16, 2), 256, 0, stream>>>(
      ff1, fc2t, ffp, nullptr, nullptr, 2048, 2048, 8192, 2);
  // out = LN(h + p0 + p1 + fc2b)
  k_add_ln<<<2048, 256, 0, stream>>>(h32, ffp, ffp + 4 * MB, fc2b, g2, b2,
                                     out, nullptr);
}

// Round 7
// 529.403 us; speedup vs baseline: 1.2936x; 1.2057x over previous
//
#include <hip/hip_runtime.h>

// TransformerBlock fused pipeline for MI355X (gfx950).
// SEQ=2048, D_MODEL=2048, H=16, DK=DV=128, DFF=8192. fp32 in/out.
//
// R7: gemm8 (8-phase 256^2, value-verified in R6) deployed for vt/out-proj/
// fc1/fc2. R3/R4's failure was NOT gemm8: the launcher had reordered the
// fused-QK weight buffers (wqh,wql,wkh,wkl instead of wqh,wkh|wql,wkl), so
// split3's B-hi rows 2048..4095 were Q-lo instead of K-hi. Adjacency is now
// structural: wkh/wkl are derived pointers (qk_bh+4M / qk_bl+4M).

typedef __bf16 bf16;
typedef __attribute__((ext_vector_type(8))) __bf16 bf16x8;
typedef __attribute__((ext_vector_type(4))) __bf16 bf16x4;
typedef __attribute__((ext_vector_type(4))) float f32x4;

#define MFMA(a, b, c) __builtin_amdgcn_mfma_f32_16x16x32_bf16((a), (b), (c), 0, 0, 0)
#define NEG_INF (-3.402823466e38f)

__device__ __forceinline__ void cp16(void* lds, const void* g) {
  __builtin_amdgcn_global_load_lds(
      (const __attribute__((address_space(1))) unsigned int*)g,
      (__attribute__((address_space(3))) unsigned int*)lds, 16, 0, 0);
}

#define SBAR() __builtin_amdgcn_sched_barrier(0)
#define GBAR()                              \
  do {                                      \
    asm volatile("" ::: "memory");          \
    __builtin_amdgcn_s_barrier();           \
    asm volatile("" ::: "memory");          \
  } while (0)
#define LGKM0()                                         \
  do {                                                  \
    asm volatile("s_waitcnt lgkmcnt(0)" ::: "memory");  \
    __builtin_amdgcn_sched_barrier(0);                  \
  } while (0)
#define VMC6()                                          \
  do {                                                  \
    asm volatile("s_waitcnt vmcnt(6)" ::: "memory");    \
    __builtin_amdgcn_sched_barrier(0);                  \
  } while (0)

// ---------------- converts ----------------

__global__ void k_split_x(const float* __restrict__ x, bf16* __restrict__ xh,
                          bf16* __restrict__ xl) {
  int i = blockIdx.x * 256 + threadIdx.x;
  f32x4 v = ((const f32x4*)x)[i];
  bf16x4 h, l;
#pragma unroll
  for (int j = 0; j < 4; ++j) {
    bf16 hi = (bf16)v[j];
    h[j] = hi;
    l[j] = (bf16)(v[j] - (float)hi);
  }
  ((bf16x4*)xh)[i] = h;
  ((bf16x4*)xl)[i] = l;
}

template <bool SPLIT>
__global__ void k_tcvt(const float* __restrict__ in, bf16* __restrict__ oh,
                       bf16* __restrict__ ol, int R, int C) {
  __shared__ float t[64][65];
  long zoff = (long)blockIdx.z * R * C;
  int c0 = blockIdx.x * 64, r0 = blockIdx.y * 64;
  int cc = threadIdx.x & 63, rr = threadIdx.x >> 6;
#pragma unroll
  for (int i = 0; i < 16; ++i) {
    int r = i * 4 + rr;
    t[r][cc] = in[zoff + (long)(r0 + r) * C + c0 + cc];
  }
  __syncthreads();
#pragma unroll
  for (int i = 0; i < 16; ++i) {
    int orow = i * 4 + rr;
    float v = t[cc][orow];
    long oidx = zoff + (long)(c0 + orow) * R + r0 + cc;
    bf16 hi = (bf16)v;
    oh[oidx] = hi;
    if (SPLIT) ol[oidx] = (bf16)(v - (float)hi);
  }
}

// combine 4 fp32 partials -> bf16
__global__ void k_combine4(const float* __restrict__ p, long pstr,
                           bf16* __restrict__ o) {
  int i = blockIdx.x * 256 + threadIdx.x;
  f32x4 v = ((const f32x4*)p)[i];
#pragma unroll
  for (int zz = 1; zz < 4; ++zz) v += ((const f32x4*)(p + zz * pstr))[i];
  bf16x4 ob;
#pragma unroll
  for (int j = 0; j < 4; ++j) ob[j] = (bf16)v[j];
  ((bf16x4*)o)[i] = ob;
}

// ---------------- 8-phase 256^2 GEMM: C[M,N] = A[M,K] @ B[N,K]^T ----------
// R6 value-verified body. 512 thr = 8 waves (2M x 4N); BK=64; 128KB dbuf LDS;
// rotated quadrants P1..P4; counted vmcnt(6); XOR swizzle both-sides.
// EPI: 0 = fp32 partial at Cf + z*M*N ; 2 = relu(v + bias) -> bf16.
template <int EPI>
__global__ __launch_bounds__(512, 1) void k_gemm8(
    const bf16* __restrict__ A, const bf16* __restrict__ B,
    float* __restrict__ Cf, bf16* __restrict__ Cb,
    const float* __restrict__ bias, int M, int N, int K, int nsplit) {
  __shared__ char lds[131072];
  const int tid = threadIdx.x, w = tid >> 6, l = tid & 63;
  const int l16 = l & 15, lg = l >> 4;
  const int wr = w >> 2, wc = w & 3;
  const long bm0 = (long)blockIdx.y * 256, bn0 = (long)blockIdx.x * 256;
  const int z = blockIdx.z;
  const int ksz = K / nsplit, kbeg = z * ksz;
  const int nt = ksz >> 6;
  const long lK = K;

  const int srow = w * 8 + (l >> 3);
  const int sslot = (l & 7) ^ (l >> 3);

  auto STAGE = [&](int bufp, int isB, int h, int tt) {
    int tc = tt < nt ? tt : nt - 1;
    char* dst = lds + bufp * 65536 + isB * 32768 + h * 16384 + w * 1024;
    const bf16* G = isB ? B : A;
    long r0 = (isB ? bn0 : bm0) + h * 128 + srow;
    const bf16* src = G + r0 * lK + kbeg + tc * 64 + sslot * 8;
    cp16(dst, src);
    cp16(dst + 8192, src + 64 * lK);
  };
  auto LDA = [&](int bufp, int mf, int ks) -> bf16x8 {
    int inrow = (mf & 3) * 32 + wr * 16 + l16;
    int byo = bufp * 65536 + (mf >> 2) * 16384 + inrow * 128 +
              ((((ks << 2) + lg) ^ (inrow & 7)) << 4);
    return *(const bf16x8*)(lds + byo);
  };
  auto LDB = [&](int bufp, int nf, int ks) -> bf16x8 {
    int inrow = (nf & 1) * 64 + wc * 16 + l16;
    int byo = bufp * 65536 + 32768 + (nf >> 1) * 16384 + inrow * 128 +
              ((((ks << 2) + lg) ^ (inrow & 7)) << 4);
    return *(const bf16x8*)(lds + byo);
  };

  f32x4 acc[8][4];
#pragma unroll
  for (int mf = 0; mf < 8; ++mf)
#pragma unroll
    for (int nf = 0; nf < 4; ++nf)
#pragma unroll
      for (int j = 0; j < 4; ++j) acc[mf][nf][j] = 0.f;

  STAGE(0, 0, 0, 0);
  STAGE(0, 1, 0, 0);
  STAGE(0, 0, 1, 0);
  STAGE(0, 1, 1, 0);
  STAGE(1, 1, 0, 1);
  STAGE(1, 0, 1, 1);
  STAGE(1, 1, 1, 1);
  SBAR();
  VMC6();
  GBAR();

  bf16x8 a[4][2], b[2][2];
  for (int t = 0; t < nt; ++t) {
    const int cb = t & 1, nb = cb ^ 1;
    // P1: A-h0 x B-h0 ; stage nb A-h0 (t+1)
#pragma unroll
    for (int mf = 0; mf < 4; ++mf)
#pragma unroll
      for (int ks = 0; ks < 2; ++ks) a[mf][ks] = LDA(cb, mf, ks);
#pragma unroll
    for (int nf = 0; nf < 2; ++nf)
#pragma unroll
      for (int ks = 0; ks < 2; ++ks) b[nf][ks] = LDB(cb, nf, ks);
    STAGE(nb, 0, 0, t + 1);
    SBAR();
    GBAR();
    LGKM0();
    __builtin_amdgcn_s_setprio(1);
#pragma unroll
    for (int mf = 0; mf < 4; ++mf)
#pragma unroll
      for (int nf = 0; nf < 2; ++nf)
#pragma unroll
        for (int ks = 0; ks < 2; ++ks)
          acc[mf][nf] = MFMA(a[mf][ks], b[nf][ks], acc[mf][nf]);
    __builtin_amdgcn_s_setprio(0);
    GBAR();
    // P2: A-h1 x B-h0 ; stage cb B-h0 (t+2)
#pragma unroll
    for (int mf = 0; mf < 4; ++mf)
#pragma unroll
      for (int ks = 0; ks < 2; ++ks) a[mf][ks] = LDA(cb, mf + 4, ks);
    STAGE(cb, 1, 0, t + 2);
    SBAR();
    GBAR();
    LGKM0();
    __builtin_amdgcn_s_setprio(1);
#pragma unroll
    for (int mf = 0; mf < 4; ++mf)
#pragma unroll
      for (int nf = 0; nf < 2; ++nf)
#pragma unroll
        for (int ks = 0; ks < 2; ++ks)
          acc[mf + 4][nf] = MFMA(a[mf][ks], b[nf][ks], acc[mf + 4][nf]);
    __builtin_amdgcn_s_setprio(0);
    GBAR();
    // P3: A-h1 x B-h1
#pragma unroll
    for (int nf = 0; nf < 2; ++nf)
#pragma unroll
      for (int ks = 0; ks < 2; ++ks) b[nf][ks] = LDB(cb, nf + 2, ks);
    GBAR();
    LGKM0();
    __builtin_amdgcn_s_setprio(1);
#pragma unroll
    for (int mf = 0; mf < 4; ++mf)
#pragma unroll
      for (int nf = 0; nf < 2; ++nf)
#pragma unroll
        for (int ks = 0; ks < 2; ++ks)
          acc[mf + 4][nf + 2] = MFMA(a[mf][ks], b[nf][ks], acc[mf + 4][nf + 2]);
    __builtin_amdgcn_s_setprio(0);
    GBAR();
    // P4: A-h0 x B-h1 ; stage cb A-h1,B-h1 (t+2) ; vmcnt(6)
#pragma unroll
    for (int mf = 0; mf < 4; ++mf)
#pragma unroll
      for (int ks = 0; ks < 2; ++ks) a[mf][ks] = LDA(cb, mf, ks);
    STAGE(cb, 0, 1, t + 2);
    STAGE(cb, 1, 1, t + 2);
    SBAR();
    VMC6();
    GBAR();
    LGKM0();
    __builtin_amdgcn_s_setprio(1);
#pragma unroll
    for (int mf = 0; mf < 4; ++mf)
#pragma unroll
      for (int nf = 0; nf < 2; ++nf)
#pragma unroll
        for (int ks = 0; ks < 2; ++ks)
          acc[mf][nf + 2] = MFMA(a[mf][ks], b[nf][ks], acc[mf][nf + 2]);
    __builtin_amdgcn_s_setprio(0);
    GBAR();
  }
  asm volatile("s_waitcnt vmcnt(0) lgkmcnt(0)" ::: "memory");

#pragma unroll
  for (int mf = 0; mf < 8; ++mf)
#pragma unroll
    for (int nf = 0; nf < 4; ++nf) {
      long col = bn0 + nf * 64 + wc * 16 + l16;
      float bv = (EPI == 2) ? bias[col] : 0.f;
#pragma unroll
      for (int jj = 0; jj < 4; ++jj) {
        long row = bm0 + mf * 32 + wr * 16 + lg * 4 + jj;
        float v = acc[mf][nf][jj];
        if (EPI == 0) {
          Cf[(long)z * M * N + row * N + col] = v;
        } else {
          v = fmaxf(v + bv, 0.f);
          Cb[row * N + col] = (bf16)v;
        }
      }
    }
}

// ---------------- split-precision GEMM (Q/K projection) ----------------
__global__ __launch_bounds__(256, 2) void k_gemm_split3(
    const bf16* __restrict__ Ah, const bf16* __restrict__ Al,
    const bf16* __restrict__ Bh, const bf16* __restrict__ Bl,
    bf16* __restrict__ Ch, bf16* __restrict__ Cl,
    int M, int N, int K, float scale, int scale_ncols) {
  __shared__ bf16 sAh[4096], sAl[4096], sBh[4096], sBl[4096];
  const int tid = threadIdx.x, w = tid >> 6, l = tid & 63;
  const int l16 = l & 15, lg = l >> 4;
  const int wr = w >> 1, wc = w & 1;
  const long bm0 = (long)blockIdx.y * 128, bn0 = (long)blockIdx.x * 128;
  f32x4 acc[4][4];
#pragma unroll
  for (int m = 0; m < 4; ++m)
#pragma unroll
    for (int n = 0; n < 4; ++n)
#pragma unroll
      for (int j = 0; j < 4; ++j) acc[m][n][j] = 0.f;

  for (int kt = 0; kt < K; kt += 32) {
    __syncthreads();
#pragma unroll
    for (int i = 0; i < 2; ++i) {
      int c = (w * 2 + i) * 64 + l;
      int row = c >> 2, seg = c & 3;
      long ao = (bm0 + row) * K + kt + seg * 8;
      long bo = (bn0 + row) * K + kt + seg * 8;
      int db = (w * 2 + i) * 512;
      cp16(&sAh[db], &Ah[ao]);
      cp16(&sAl[db], &Al[ao]);
      cp16(&sBh[db], &Bh[bo]);
      cp16(&sBl[db], &Bl[bo]);
    }
    __syncthreads();
    bf16x8 ah[4], al[4], bh[4], bl[4];
#pragma unroll
    for (int m = 0; m < 4; ++m) {
      int off = (wr * 64 + m * 16 + l16) * 32 + lg * 8;
      ah[m] = *(const bf16x8*)&sAh[off];
      al[m] = *(const bf16x8*)&sAl[off];
    }
#pragma unroll
    for (int n = 0; n < 4; ++n) {
      int off = (wc * 64 + n * 16 + l16) * 32 + lg * 8;
      bh[n] = *(const bf16x8*)&sBh[off];
      bl[n] = *(const bf16x8*)&sBl[off];
    }
#pragma unroll
    for (int m = 0; m < 4; ++m)
#pragma unroll
      for (int n = 0; n < 4; ++n) {
        acc[m][n] = MFMA(ah[m], bh[n], acc[m][n]);
        acc[m][n] = MFMA(ah[m], bl[n], acc[m][n]);
        acc[m][n] = MFMA(al[m], bh[n], acc[m][n]);
      }
  }
#pragma unroll
  for (int m = 0; m < 4; ++m)
#pragma unroll
    for (int n = 0; n < 4; ++n) {
      long col = bn0 + wc * 64 + n * 16 + l16;
      float sc = (col < scale_ncols) ? scale : 1.0f;
#pragma unroll
      for (int j = 0; j < 4; ++j) {
        long row = bm0 + wr * 64 + m * 16 + lg * 4 + j;
        float v = acc[m][n][j] * sc;
        bf16 hi = (bf16)v;
        Ch[row * N + col] = hi;
        Cl[row * N + col] = (bf16)(v - (float)hi);
      }
    }
}

// ---------------- flash attention (R2-exact) ----------------
__global__ __launch_bounds__(256, 2) void k_flash(
    const bf16* __restrict__ Qh, const bf16* __restrict__ Ql,
    const bf16* __restrict__ Kh, const bf16* __restrict__ Kl,
    const bf16* __restrict__ Vt, bf16* __restrict__ Oc) {
  __shared__ bf16 sm[28672];
  bf16* sKh = sm;
  bf16* sKl = sm + 8192;
  bf16* sVt = sm + 16384;
  bf16* sP = sm + 24576;
  const int tid = threadIdx.x, w = tid >> 6, l = tid & 63;
  const int l16 = l & 15, lg = l >> 4;
  const int head = blockIdx.y;
  const long q0 = (long)blockIdx.x * 64;

  bf16x8 qh_r[4], ql_r[4];
#pragma unroll
  for (int kk = 0; kk < 4; ++kk) {
    long off = (q0 + w * 16 + l16) * 4096 + head * 128 + kk * 32 + lg * 8;
    qh_r[kk] = *(const bf16x8*)&Qh[off];
    ql_r[kk] = *(const bf16x8*)&Ql[off];
  }

  f32x4 acc_o[8];
#pragma unroll
  for (int n = 0; n < 8; ++n)
#pragma unroll
    for (int j = 0; j < 4; ++j) acc_o[n][j] = 0.f;
  float mrow[4], lrow[4];
#pragma unroll
  for (int j = 0; j < 4; ++j) {
    mrow[j] = NEG_INF;
    lrow[j] = 0.f;
  }

  for (int t0 = 0; t0 < 2048; t0 += 64) {
    __syncthreads();
#pragma unroll
    for (int i = 0; i < 4; ++i) {
      int c = (w * 4 + i) * 64 + l;
      int rk = c >> 4, sk = (c & 15) ^ (rk & 7);
      long ko = (long)(t0 + rk) * 4096 + head * 128 + sk * 8;
      int db = (w * 4 + i) * 512;
      cp16(&sKh[db], &Kh[ko]);
      cp16(&sKl[db], &Kl[ko]);
      int rv = c >> 3, sv = (c & 7) ^ (rv & 7);
      long vo = (long)(head * 128 + rv) * 2048 + t0 + sv * 8;
      cp16(&sVt[db], &Vt[vo]);
    }
    __syncthreads();

    f32x4 s[4];
#pragma unroll
    for (int n = 0; n < 4; ++n)
#pragma unroll
      for (int j = 0; j < 4; ++j) s[n][j] = 0.f;
#pragma unroll
    for (int kk = 0; kk < 4; ++kk) {
      bf16x8 bh[4], bl[4];
#pragma unroll
      for (int n = 0; n < 4; ++n) {
        int r = n * 16 + l16;
        int byo = r * 256 + (((kk * 4 + lg) ^ (r & 7)) << 4);
        bh[n] = *(const bf16x8*)((const char*)sKh + byo);
        bl[n] = *(const bf16x8*)((const char*)sKl + byo);
      }
#pragma unroll
      for (int n = 0; n < 4; ++n) {
        s[n] = MFMA(qh_r[kk], bh[n], s[n]);
        s[n] = MFMA(qh_r[kk], bl[n], s[n]);
        s[n] = MFMA(ql_r[kk], bh[n], s[n]);
      }
    }

#pragma unroll
    for (int j = 0; j < 4; ++j) {
      float mx = fmaxf(fmaxf(s[0][j], s[1][j]), fmaxf(s[2][j], s[3][j]));
      mx = fmaxf(mx, __shfl_xor(mx, 1));
      mx = fmaxf(mx, __shfl_xor(mx, 2));
      mx = fmaxf(mx, __shfl_xor(mx, 4));
      mx = fmaxf(mx, __shfl_xor(mx, 8));
      float mo = mrow[j];
      float mn = fmaxf(mo, mx);
      mrow[j] = mn;
      float f = __expf(mo - mn);
      int prow = w * 16 + lg * 4 + j;
      float ssum = 0.f;
#pragma unroll
      for (int n = 0; n < 4; ++n) {
        float p = __expf(s[n][j] - mn);
        ssum += p;
        int byo = prow * 128 + (((n * 16 + l16) * 2) ^ ((prow & 7) << 4));
        *(bf16*)((char*)sP + byo) = (bf16)p;
      }
      ssum += __shfl_xor(ssum, 1);
      ssum += __shfl_xor(ssum, 2);
      ssum += __shfl_xor(ssum, 4);
      ssum += __shfl_xor(ssum, 8);
      lrow[j] = lrow[j] * f + ssum;
#pragma unroll
      for (int n = 0; n < 8; ++n) acc_o[n][j] *= f;
    }

#pragma unroll
    for (int kk = 0; kk < 2; ++kk) {
      bf16x8 pa, bv[8];
      {
        int r = w * 16 + l16;
        int byo = r * 128 + (((kk * 4 + lg) ^ (r & 7)) << 4);
        pa = *(const bf16x8*)((const char*)sP + byo);
      }
#pragma unroll
      for (int n = 0; n < 8; ++n) {
        int r = n * 16 + l16;
        int byo = r * 128 + (((kk * 4 + lg) ^ (r & 7)) << 4);
        bv[n] = *(const bf16x8*)((const char*)sVt + byo);
      }
#pragma unroll
      for (int n = 0; n < 8; ++n) acc_o[n] = MFMA(pa, bv[n], acc_o[n]);
    }
  }

#pragma unroll
  for (int j = 0; j < 4; ++j) {
    float rinv = 1.f / lrow[j];
    long row = q0 + w * 16 + lg * 4 + j;
#pragma unroll
    for (int n = 0; n < 8; ++n)
      Oc[row * 2048 + head * 128 + n * 16 + l16] = (bf16)(acc_o[n][j] * rinv);
  }
}

// ---------------- residual + np partials + LayerNorm ----------------
__global__ __launch_bounds__(256) void k_add_ln(
    const float* __restrict__ a, const float* __restrict__ p, long pstr,
    int np, const float* __restrict__ bias, const float* __restrict__ g,
    const float* __restrict__ be, float* __restrict__ o32,
    bf16* __restrict__ obf) {
  __shared__ float red[8];
  int row = blockIdx.x, tid = threadIdx.x;
  const float* pa = a + (long)row * 2048;
  f32x4 v[2];
  float sum = 0.f, sq = 0.f;
#pragma unroll
  for (int i = 0; i < 2; ++i) {
    int idx = i * 1024 + tid * 4;
    v[i] = *(const f32x4*)(pa + idx);
    for (int zz = 0; zz < np; ++zz)
      v[i] += *(const f32x4*)(p + zz * pstr + (long)row * 2048 + idx);
    if (bias != nullptr) v[i] += *(const f32x4*)(bias + idx);
#pragma unroll
    for (int j = 0; j < 4; ++j) {
      sum += v[i][j];
      sq += v[i][j] * v[i][j];
    }
  }
#pragma unroll
  for (int o = 1; o < 64; o <<= 1) {
    sum += __shfl_xor(sum, o);
    sq += __shfl_xor(sq, o);
  }
  int w = tid >> 6;
  if ((tid & 63) == 0) {
    red[w * 2] = sum;
    red[w * 2 + 1] = sq;
  }
  __syncthreads();
  sum = red[0] + red[2] + red[4] + red[6];
  sq = red[1] + red[3] + red[5] + red[7];
  float mu = sum * (1.f / 2048.f);
  float var = sq * (1.f / 2048.f) - mu * mu;
  float rs = rsqrtf(var + 1e-5f);
#pragma unroll
  for (int i = 0; i < 2; ++i) {
    int idx = i * 1024 + tid * 4;
    f32x4 vg = *(const f32x4*)(g + idx);
    f32x4 vb = *(const f32x4*)(be + idx);
    f32x4 o;
#pragma unroll
    for (int j = 0; j < 4; ++j) o[j] = (v[i][j] - mu) * rs * vg[j] + vb[j];
    *(f32x4*)(o32 + (long)row * 2048 + idx) = o;
    if (obf != nullptr) {
      bf16x4 ob;
#pragma unroll
      for (int j = 0; j < 4; ++j) ob[j] = (bf16)o[j];
      *(bf16x4*)(obf + (long)row * 2048 + idx) = ob;
    }
  }
}

// ---------------- launch ----------------
extern "C" void kernel_launch(void* const* d_in, const int* in_sizes, int n_in,
                              void* d_out, int out_size, void* d_ws, size_t ws_size,
                              hipStream_t stream) {
  const float* x    = (const float*)d_in[0];
  const float* wq   = (const float*)d_in[1];
  const float* wk   = (const float*)d_in[2];
  const float* wv   = (const float*)d_in[3];
  const float* wp   = (const float*)d_in[4];
  const float* g1   = (const float*)d_in[5];
  const float* b1   = (const float*)d_in[6];
  const float* fc1w = (const float*)d_in[7];
  const float* fc1b = (const float*)d_in[8];
  const float* fc2w = (const float*)d_in[9];
  const float* fc2b = (const float*)d_in[10];
  const float* g2   = (const float*)d_in[11];
  const float* b2   = (const float*)d_in[12];
  float* out = (float*)d_out;

  char* ws = (char*)d_ws;
  const size_t MB = 1024 * 1024;
  if (ws_size < 216 * MB) return;
  const long W4M = 4L * 1024 * 1024;     // 4M bf16 elements = one 2048x2048

  // Weight buffers. ADJACENCY CONSTRAINT (split3 B operands span both):
  //   qk_bh = [wq^T | wk^T] hi as ONE [4096][2048]; qk_bl likewise lo.
  bf16* xh    = (bf16*)(ws + 0 * MB);
  bf16* xl    = (bf16*)(ws + 8 * MB);
  bf16* qk_bh = (bf16*)(ws + 16 * MB);   // 16MB [4096][2048] hi
  bf16* qk_bl = (bf16*)(ws + 32 * MB);   // 16MB [4096][2048] lo
  bf16* wvt   = (bf16*)(ws + 48 * MB);
  bf16* wpt   = (bf16*)(ws + 56 * MB);
  bf16* fc1t  = (bf16*)(ws + 64 * MB);   // 32MB
  bf16* fc2t  = (bf16*)(ws + 96 * MB);   // 32MB
  // dynamics (time-multiplexed 128..216MB + 0..64MB after weights die):
  float* vtp  = (float*)(ws + 128 * MB); // 4x16MB vt partials
  bf16* vtb   = (bf16*)(ws + 192 * MB);  // 8MB V^T bf16
  bf16* qkh   = (bf16*)(ws + 128 * MB);  // 16MB [2048][4096] (vtp dead)
  bf16* qkl   = (bf16*)(ws + 144 * MB);  // 16MB
  bf16* cc    = (bf16*)(ws + 200 * MB);  // 8MB concat
  float* aop  = (float*)(ws + 128 * MB); // 4x16MB out-proj partials (qk dead)
  float* h32  = (float*)(ws + 160 * MB); // 16MB (within old qk/aop area? no:
                                         //  aop is 128..192; use 192..208)
  bf16*  hbf  = (bf16*)(ws + 208 * MB);  // 8MB
  bf16*  ff1  = (bf16*)(ws + 128 * MB);  // 32MB (aop dead after LN1)
  float* ffp  = (float*)(ws + 0 * MB);   // 4x16MB fc2 partials (x/qk_b dead)
  h32 = (float*)(ws + 192 * MB);         // 16MB: vtb dead after flash, cc dead
                                         // after out-proj; 192..208 free at LN1
  const long PSTR = 4194304L;            // 16MB in floats

  // converts
  k_split_x<<<4096, 256, 0, stream>>>(x, xh, xl);
  k_tcvt<true ><<<dim3(2, 32, 16), 256, 0, stream>>>(wq, qk_bh, qk_bl, 2048, 128);
  k_tcvt<true ><<<dim3(2, 32, 16), 256, 0, stream>>>(wk, qk_bh + W4M, qk_bl + W4M,
                                                     2048, 128);
  k_tcvt<false><<<dim3(2, 32, 16), 256, 0, stream>>>(wv, wvt, nullptr, 2048, 128);
  k_tcvt<false><<<dim3(32, 32, 1), 256, 0, stream>>>(wp, wpt, nullptr, 2048, 2048);
  k_tcvt<false><<<dim3(128, 32, 1), 256, 0, stream>>>(fc1w, fc1t, nullptr, 2048, 8192);
  k_tcvt<false><<<dim3(32, 128, 1), 256, 0, stream>>>(fc2w, fc2t, nullptr, 8192, 2048);

  // V^T = wvt @ xh^T  (8-phase, split-K=4) -> combine to bf16
  k_gemm8<0><<<dim3(8, 8, 4), 512, 0, stream>>>(
      wvt, xh, vtp, nullptr, nullptr, 2048, 2048, 2048, 4);
  k_combine4<<<4096, 256, 0, stream>>>(vtp, PSTR, vtb);
  // fused Q,K projection (split3), 1/sqrt(128) folded into Q cols
  k_gemm_split3<<<dim3(32, 16), 256, 0, stream>>>(
      xh, xl, qk_bh, qk_bl, qkh, qkl, 2048, 4096, 2048,
      0.08838834764831845f, 2048);
  // attention -> concat
  k_flash<<<dim3(32, 16), 256, 0, stream>>>(qkh, qkl, qkh + 2048, qkl + 2048,
                                            vtb, cc);
  // out projection (8-phase, split-K=4; partials combined in LN1)
  k_gemm8<0><<<dim3(8, 8, 4), 512, 0, stream>>>(
      cc, wpt, aop, nullptr, nullptr, 2048, 2048, 2048, 4);
  // h = LN(x + sum aop)
  k_add_ln<<<2048, 256, 0, stream>>>(x, aop, PSTR, 4, nullptr, g1, b1, h32, hbf);
  // ff1 = relu(h @ fc1 + b1)  (8-phase, direct epilogue)
  k_gemm8<2><<<dim3(32, 8, 1), 512, 0, stream>>>(
      hbf, fc1t, nullptr, ff1, fc1b, 2048, 8192, 2048, 1);
  // ff2 partials (8-phase, split-K=4 over K=8192)
  k_gemm8<0><<<dim3(8, 8, 4), 512, 0, stream>>>(
      ff1, fc2t, ffp, nullptr, nullptr, 2048, 2048, 8192, 4);
  // out = LN(h + sum ffp + fc2b)
  k_add_ln<<<2048, 256, 0, stream>>>(h32, ffp, PSTR, 4, fc2b, g2, b2, out, nullptr);
}